// Round 1
// baseline (6975.494 us; speedup 1.0000x reference)
//
#include <hip/hip_runtime.h>
#include <hip/hip_bf16.h>

#define DD 256
#define HH 8
#define DH 32
#define SS 512
#define MM 1024
#define BB 16
#define FF 1024
#define LL 6
#define VV 3000
#define QT 256   // q rows per attention block
#define TJ 64    // K/V rows staged per LDS tile

typedef __bf16 bf16x8 __attribute__((ext_vector_type(8)));
typedef float  f32x4  __attribute__((ext_vector_type(4)));

// Mixed-dtype load: bf==1 -> bf16, bf==0 -> fp32.
__device__ __forceinline__ float ldx(const void* p, size_t i, int bf) {
    if (bf) return __bfloat162float(((const __hip_bfloat16*)p)[i]);
    return ((const float*)p)[i];
}

// fp32 -> bf16 hi/lo split: v = hi + lo + O(2^-17 * v)
__device__ __forceinline__ void split1(float v, __bf16& h, __bf16& l) {
    h = (__bf16)v;
    l = (__bf16)(v - (float)h);
}

// dtype detector: writes 1 if buffer is bf16, 0 if fp32.
__global__ void detect_k(const unsigned int* __restrict__ w, int* __restrict__ flag) {
    int t = threadIdx.x;
    unsigned int v = w[t];
    int ok = 1;
#pragma unroll
    for (int h = 0; h < 2; ++h) {
        unsigned int hw = (v >> (16 * h)) & 0xFFFFu;
        unsigned int e = (hw >> 7) & 0xFFu;
        if (!((e >= 90u && e <= 140u) || (hw & 0x7FFFu) == 0u)) ok = 0;
    }
    __shared__ int allok;
    if (t == 0) allok = 1;
    __syncthreads();
    if (!ok) atomicAnd(&allok, 0);
    __syncthreads();
    if (t == 0) *flag = allok;
}

// x = input_embed[seq] + pos_embed ; also writes hi/lo split of x
__global__ void embed_k(const int* __restrict__ seq,
                        const void* __restrict__ emb,
                        const void* __restrict__ pos,
                        float* __restrict__ x,
                        __bf16* __restrict__ xh,
                        __bf16* __restrict__ xl,
                        const int* __restrict__ flagp) {
    int bf = *flagp;
    int row = blockIdx.x;           // b*512 + s
    int d = threadIdx.x;            // 0..255
    int s = row & (SS - 1);
    int b = row >> 9;
    int tok = seq[b * SS + s];
    float v = ldx(emb, (size_t)tok * DD + d, bf) + ldx(pos, (size_t)s * DD + d, bf);
    size_t idx = (size_t)row * DD + d;
    x[idx] = v;
    split1(v, xh[idx], xl[idx]);
}

// ---------------------------------------------------------------------------
// Split-bf16 MFMA GEMM.  C[M,N] = A[M,K] @ B[K,N] (+bias)(+relu)
//   AMODE 1: A is flag-dtype global (fp32/bf16), split in-kernel (encoded)
//   AMODE 2: A is pre-split pair (A = hi array, Al_ = lo array, bf16)
//   BTRANS 0: B row-major [K][N] weights; 1: B is [N][K] (embedding, guarded)
//   OUTMODE 0: fp32 C; 1: split pair C/C2 (bf16 hi/lo); 2: flag-dtype store
//   nsplit>0: B / C are nmat stacked [K][nsplit] / [M][nsplit] matrices,
//             block's sub-matrix = n0/nsplit, C base advanced by mat*cstride.
// Tile: BM=128 BN=64 BK=32, 128 threads = 2 waves, wave tile 64x64 (4x4 frags
// of v_mfma_f32_16x16x32_bf16). Per frag-pair: hi*hi + lo*hi + hi*lo.
// Bs is [n][k] with 16B XOR swizzle (k ^= (n&3)<<3) -> conflict-free b128 reads.
// ---------------------------------------------------------------------------
template <int AMODE, int BTRANS, int OUTMODE>
__global__ __launch_bounds__(128, 2)
void gemm_mfma_k(const void* __restrict__ A, const void* __restrict__ Al_,
                 const char* __restrict__ Bbase, size_t boff,
                 const char* __restrict__ biasbase, size_t biasoff, int hasbias,
                 void* __restrict__ C, void* __restrict__ C2,
                 int M, int N, int K, int relu,
                 int nsplit, size_t cstride,
                 const int* __restrict__ flagp) {
    int bfw = *flagp;
    int esz = bfw ? 2 : 4;
    const char* Bw = Bbase + boff * esz;
    int t = threadIdx.x;
    int lane = t & 63;
    int wv = t >> 6;                 // wave id: rows wv*64..wv*64+63
    int n0 = blockIdx.x * 64;
    int m0 = blockIdx.y * 128;
    int ldb = N, ldc = N;
    float* Cf = (float*)C;
    if (nsplit) {
        int mat = n0 / nsplit;
        n0 -= mat * nsplit;
        Bw += (size_t)mat * K * nsplit * esz;
        Cf += (size_t)mat * cstride;
        ldb = ldc = nsplit;
    }

    __shared__ __align__(16) __bf16 Ah[128][32];
    __shared__ __align__(16) __bf16 Al[128][32];
    __shared__ __align__(16) __bf16 Bh[64][32];
    __shared__ __align__(16) __bf16 Bl[64][32];

    f32x4 acc[4][4] = {};
    int fr = lane & 15;              // frag row (A) / col (B,C)
    int fg = lane >> 4;              // k-group 0..3
    int t_alo = !(AMODE == 1 && bfw);   // A_lo term needed?
    int t_blo = !bfw;                   // B_lo term needed?

    for (int k0 = 0; k0 < K; k0 += 32) {
        // ---- stage A tile [128][32] ----
        if (AMODE == 2) {
            const __bf16* Ahg = (const __bf16*)A;
            const __bf16* Alg = (const __bf16*)Al_;
#pragma unroll
            for (int i = 0; i < 4; ++i) {
                int c = i * 128 + t;
                int row = c >> 2, kc = (c & 3) * 8;
                size_t g = (size_t)(m0 + row) * K + k0 + kc;
                *(bf16x8*)&Ah[row][kc] = *(const bf16x8*)(Ahg + g);
                *(bf16x8*)&Al[row][kc] = *(const bf16x8*)(Alg + g);
            }
        } else {  // AMODE==1: flag-dtype global, split in-kernel
#pragma unroll
            for (int i = 0; i < 8; ++i) {
                int row = i * 16 + (t >> 3);
                int kc = (t & 7) * 4;
                size_t g = (size_t)(m0 + row) * K + k0 + kc;
                float va[4];
                if (bfw) {
#pragma unroll
                    for (int j = 0; j < 4; ++j)
                        va[j] = __bfloat162float(((const __hip_bfloat16*)A)[g + j]);
                } else {
                    float4 f4 = *(const float4*)((const float*)A + g);
                    va[0] = f4.x; va[1] = f4.y; va[2] = f4.z; va[3] = f4.w;
                }
#pragma unroll
                for (int j = 0; j < 4; ++j)
                    split1(va[j], Ah[row][kc + j], Al[row][kc + j]);
            }
        }
        // ---- stage B tile -> Bs[n][k] swizzled ----
        if (BTRANS == 0) {
            int n = t & 63, g2 = t >> 6;
#pragma unroll
            for (int half = 0; half < 2; ++half) {
                int kb = g2 * 16 + half * 8;
                bf16x8 hv, lv;
#pragma unroll
                for (int i = 0; i < 8; ++i) {
                    float v = ldx(Bw, (size_t)(k0 + kb + i) * ldb + n0 + n, bfw);
                    __bf16 h, l; split1(v, h, l);
                    hv[i] = h; lv[i] = l;
                }
                int ke = kb ^ ((n & 3) << 3);
                *(bf16x8*)&Bh[n][ke] = hv;
                *(bf16x8*)&Bl[n][ke] = lv;
            }
        } else {  // B is [N][K] row-major (shared embedding), guard N
            int n = t >> 1, half = t & 1;
            int ok = (n0 + n) < N;
#pragma unroll
            for (int q = 0; q < 2; ++q) {
                int kb = half * 16 + q * 8;
                bf16x8 hv, lv;
#pragma unroll
                for (int i = 0; i < 8; ++i) {
                    float v = ok ? ldx(Bw, (size_t)(n0 + n) * K + k0 + kb + i, bfw) : 0.f;
                    __bf16 h, l; split1(v, h, l);
                    hv[i] = h; lv[i] = l;
                }
                int ke = kb ^ ((n & 3) << 3);
                *(bf16x8*)&Bh[n][ke] = hv;
                *(bf16x8*)&Bl[n][ke] = lv;
            }
        }
        __syncthreads();

        // ---- fragments + MFMA ----
        bf16x8 afh[4], afl[4], bgh[4], bgl[4];
#pragma unroll
        for (int f = 0; f < 4; ++f) {
            int ar = wv * 64 + f * 16 + fr;
            afh[f] = *(const bf16x8*)&Ah[ar][fg * 8];
            afl[f] = *(const bf16x8*)&Al[ar][fg * 8];
            int bn = f * 16 + fr;
            int ke = (fg * 8) ^ ((bn & 3) << 3);
            bgh[f] = *(const bf16x8*)&Bh[bn][ke];
            bgl[f] = *(const bf16x8*)&Bl[bn][ke];
        }
#pragma unroll
        for (int mf = 0; mf < 4; ++mf)
#pragma unroll
            for (int nf = 0; nf < 4; ++nf) {
                acc[mf][nf] = __builtin_amdgcn_mfma_f32_16x16x32_bf16(afh[mf], bgh[nf], acc[mf][nf], 0, 0, 0);
                if (t_alo)
                    acc[mf][nf] = __builtin_amdgcn_mfma_f32_16x16x32_bf16(afl[mf], bgh[nf], acc[mf][nf], 0, 0, 0);
                if (t_blo)
                    acc[mf][nf] = __builtin_amdgcn_mfma_f32_16x16x32_bf16(afh[mf], bgl[nf], acc[mf][nf], 0, 0, 0);
            }
        __syncthreads();
    }

    // ---- epilogue ----
    const char* biasp = biasbase + biasoff * esz;
#pragma unroll
    for (int mf = 0; mf < 4; ++mf)
#pragma unroll
        for (int nf = 0; nf < 4; ++nf)
#pragma unroll
            for (int r = 0; r < 4; ++r) {
                int row = m0 + wv * 64 + mf * 16 + fg * 4 + r;
                int col = n0 + nf * 16 + fr;
                float v = acc[mf][nf][r];
                if (OUTMODE == 2) {
                    if (col < N) {
                        v += ldx(biasp, col, bfw);
                        size_t oi = (size_t)row * N + col;
                        if (bfw) ((__hip_bfloat16*)C)[oi] = __float2bfloat16(v);
                        else     ((float*)C)[oi] = v;
                    }
                } else {
                    if (hasbias) v += ldx(biasp, col, bfw);
                    if (relu) v = fmaxf(v, 0.f);
                    size_t oi = (size_t)row * ldc + col;
                    if (OUTMODE == 1) {
                        __bf16 h, l; split1(v, h, l);
                        ((__bf16*)C)[oi]  = h;
                        ((__bf16*)C2)[oi] = l;
                    } else {
                        Cf[oi] = v;
                    }
                }
            }
}

// Tiled attention (unchanged math, fp32 SIMT): block = (b, h, q-tile of QT rows),
// one q-row per thread. Output written as bf16 hi/lo split (feeds o-proj GEMM).
template <int CAUSAL>
__global__ void attn_tile_k(const float* __restrict__ Q,
                            const float* __restrict__ K,
                            const float* __restrict__ V,
                            __bf16* __restrict__ Oh,
                            __bf16* __restrict__ Ol,
                            int Sk) {
    __shared__ float Ks[TJ][DH];
    __shared__ float Vs[TJ][DH];
    int tid = threadIdx.x;
    int blk = blockIdx.x;                   // ((b*HH + h)*NQT + qt), NQT=2
    int qt = blk & 1;
    int h  = (blk >> 1) & (HH - 1);
    int b  = blk >> 4;
    int q  = qt * QT + tid;
    int wave_qmax = qt * QT + (tid | 63);   // wave-uniform

    const float* qp = Q + ((size_t)b * SS + q) * DD + h * DH;
    float4 qr[8];
#pragma unroll
    for (int i = 0; i < 8; ++i) qr[i] = ((const float4*)qp)[i];
    float4 o4[8];
#pragma unroll
    for (int i = 0; i < 8; ++i) o4[i] = make_float4(0.f, 0.f, 0.f, 0.f);
    float m = -1e30f, l = 0.f;
    const float scale = 0.17677669529663689f;  // 1/sqrt(32)

    int ntiles = CAUSAL ? ((qt + 1) * QT) / TJ : Sk / TJ;
    int r0 = tid >> 3;                      // 0..31
    int e0 = (tid & 7) * 4;                 // 0,4,..,28

    for (int t = 0; t < ntiles; ++t) {
        int j0 = t * TJ;
#pragma unroll
        for (int half = 0; half < 2; ++half) {
            int r = r0 + half * 32;
            const float* kp = K + ((size_t)b * Sk + j0 + r) * DD + h * DH + e0;
            const float* vp = V + ((size_t)b * Sk + j0 + r) * DD + h * DH + e0;
            *(float4*)&Ks[r][e0] = *(const float4*)kp;
            *(float4*)&Vs[r][e0] = *(const float4*)vp;
        }
        __syncthreads();

        if (!CAUSAL || j0 <= wave_qmax) {
            int jjend = CAUSAL ? min(TJ, wave_qmax - j0 + 1) : TJ;
            for (int jj = 0; jj < jjend; ++jj) {
                float s = 0.f;
                const float4* kr = (const float4*)Ks[jj];
#pragma unroll
                for (int i = 0; i < 8; ++i) {
                    float4 kv = kr[i];
                    s += qr[i].x * kv.x + qr[i].y * kv.y + qr[i].z * kv.z + qr[i].w * kv.w;
                }
                s *= scale;
                if (CAUSAL && (j0 + jj) > q) s = -1e30f;
                float mnew = fmaxf(m, s);
                float alpha = __expf(m - mnew);
                float p = __expf(s - mnew);
                l = l * alpha + p;
                const float4* vr = (const float4*)Vs[jj];
#pragma unroll
                for (int i = 0; i < 8; ++i) {
                    float4 vv = vr[i];
                    o4[i].x = o4[i].x * alpha + p * vv.x;
                    o4[i].y = o4[i].y * alpha + p * vv.y;
                    o4[i].z = o4[i].z * alpha + p * vv.z;
                    o4[i].w = o4[i].w * alpha + p * vv.w;
                }
                m = mnew;
            }
        }
        __syncthreads();
    }

    float inv = 1.f / l;
    size_t obase = ((size_t)b * SS + q) * DD + h * DH;
    __bf16 ohv[32], olv[32];
#pragma unroll
    for (int i = 0; i < 8; ++i) {
        float vv[4] = {o4[i].x * inv, o4[i].y * inv, o4[i].z * inv, o4[i].w * inv};
#pragma unroll
        for (int j = 0; j < 4; ++j) split1(vv[j], ohv[i * 4 + j], olv[i * 4 + j]);
    }
#pragma unroll
    for (int i = 0; i < 4; ++i) {
        *(bf16x8*)(Oh + obase + i * 8) = *(const bf16x8*)&ohv[i * 8];
        *(bf16x8*)(Ol + obase + i * 8) = *(const bf16x8*)&olv[i * 8];
    }
}

// x = LN(x + h); also writes hi/lo split of new x.
__global__ void add_ln_k(float* __restrict__ x,
                         const float* __restrict__ hbuf,
                         __bf16* __restrict__ xh,
                         __bf16* __restrict__ xl,
                         const char* __restrict__ gbase, size_t goff,
                         const char* __restrict__ bbase, size_t boff,
                         const int* __restrict__ flagp) {
    int bf = *flagp;
    const void* g = gbase + goff * (bf ? 2 : 4);
    const void* bb = bbase + boff * (bf ? 2 : 4);
    int row = blockIdx.x;
    int d = threadIdx.x;                 // 256 threads, one per element
    float v = x[(size_t)row * DD + d];
    if (hbuf) v += hbuf[(size_t)row * DD + d];
    float s = v, s2 = v * v;
#pragma unroll
    for (int off = 32; off > 0; off >>= 1) {
        s += __shfl_down(s, off);
        s2 += __shfl_down(s2, off);
    }
    __shared__ float sh[8];
    int w = d >> 6;
    if ((d & 63) == 0) { sh[w] = s; sh[4 + w] = s2; }
    __syncthreads();
    if (d == 0) {
        sh[0] = sh[0] + sh[1] + sh[2] + sh[3];
        sh[4] = sh[4] + sh[5] + sh[6] + sh[7];
    }
    __syncthreads();
    float mu = sh[0] * (1.f / DD);
    float var = fmaxf(sh[4] * (1.f / DD) - mu * mu, 0.f);
    float inv = rsqrtf(var + 1e-5f);
    float o = (v - mu) * inv * ldx(g, d, bf) + ldx(bb, d, bf);
    size_t idx = (size_t)row * DD + d;
    x[idx] = o;
    split1(o, xh[idx], xl[idx]);
}

extern "C" void kernel_launch(void* const* d_in, const int* in_sizes, int n_in,
                              void* d_out, int out_size, void* d_ws, size_t ws_size,
                              hipStream_t stream) {
    const void* encoded     = d_in[0];
    const int*  seq         = (const int*)d_in[1];
    const void* input_embed = d_in[2];
    const void* pos_embed   = d_in[3];
    const void* output_bias = d_in[4];
    const char* sa_qkv      = (const char*)d_in[5];
    const char* sa_o        = (const char*)d_in[6];
    const char* ca_q        = (const char*)d_in[7];
    const char* ca_kv       = (const char*)d_in[8];
    const char* ca_o        = (const char*)d_in[9];
    const char* ffn_w1      = (const char*)d_in[10];
    const char* ffn_b1      = (const char*)d_in[11];
    const char* ffn_w2      = (const char*)d_in[12];
    const char* ffn_b2      = (const char*)d_in[13];
    const char* ln_g        = (const char*)d_in[14];
    const char* ln_b        = (const char*)d_in[15];
    const char* fin_g       = (const char*)d_in[16];
    const char* fin_b       = (const char*)d_in[17];

    const size_t NTOK = (size_t)BB * SS;          // 8192
    const size_t NENC = (size_t)BB * MM;          // 16384

    // Workspace (~56 MiB, same footprint as verified layout):
    int*    flag = (int*)d_ws;
    float*  x  = (float*)d_ws + 64;               // 8 MiB
    __bf16* xh = (__bf16*)(x + NTOK * DD);        // 4 MiB
    __bf16* xl = xh + NTOK * DD;                  // 4 MiB
    float*  Qb = (float*)(xl + NTOK * DD);        // 8 MiB
    float*  Kb = Qb + NTOK * DD;                  // 16 MiB (cross K / FFN hidden hi)
    float*  Vb = Kb + NENC * DD;                  // 16 MiB (cross V / FFN hidden lo)
    // aliases (stream-ordered, verified no overlap in lifetime):
    float*  Tb  = Qb;                 // gemm temp after attention
    __bf16* obh = xh;                 // attn O split: xh/xl dead between
    __bf16* obl = xl;                 //   QKV-read and next add_ln write
    __bf16* hbh = (__bf16*)Kb;        // FFN hidden split (Kb/Vb dead post-attn)
    __bf16* hbl = (__bf16*)Vb;

    detect_k<<<1, 256, 0, stream>>>((const unsigned int*)input_embed, flag);
    embed_k<<<NTOK, 256, 0, stream>>>(seq, input_embed, pos_embed, x, xh, xl, flag);

    dim3 blk(128);
    dim3 gQKV(12, 64);                 // fused QKV, N=768 as 3x[256]
    dim3 gP(4, 64);                    // N=256, M=8192 projections
    dim3 gCKV(8, 128);                 // fused cross K/V, N=512, M=16384
    dim3 gW1(16, 64);                  // N=1024
    dim3 gOut(47, 64);                 // N=3000 (guarded)
    int attn_blocks = BB * HH * (SS / QT);        // 256

    for (int l = 0; l < LL; ++l) {
        size_t oQKV = (size_t)l * 3 * DD * DD;
        size_t oO   = (size_t)l * DD * DD;
        size_t oCKV = (size_t)l * 2 * DD * DD;
        size_t oW1  = (size_t)l * DD * FF;
        size_t oB1  = (size_t)l * FF;
        size_t oW2  = (size_t)l * FF * DD;
        size_t oB2  = (size_t)l * DD;
        size_t oG   = (size_t)l * 3 * DD;

        // --- self attention: fused QKV (Q->Qb, K->Qb+2M=Kb, V->Qb+4M) ---
        gemm_mfma_k<2, 0, 0><<<gQKV, blk, 0, stream>>>(xh, xl, sa_qkv, oQKV,
            nullptr, 0, 0, Qb, nullptr, (int)NTOK, 3 * DD, DD, 0, DD, NTOK * DD, flag);
        attn_tile_k<1><<<attn_blocks, 256, 0, stream>>>(Qb, Kb, Kb + NTOK * DD, obh, obl, SS);
        gemm_mfma_k<2, 0, 0><<<gP, blk, 0, stream>>>(obh, obl, sa_o, oO,
            nullptr, 0, 0, Tb, nullptr, (int)NTOK, DD, DD, 0, 0, 0, flag);
        add_ln_k<<<NTOK, 256, 0, stream>>>(x, Tb, xh, xl, ln_g, oG, ln_b, oG, flag);
        // --- cross attention ---
        gemm_mfma_k<2, 0, 0><<<gP, blk, 0, stream>>>(xh, xl, ca_q, oO,
            nullptr, 0, 0, Qb, nullptr, (int)NTOK, DD, DD, 0, 0, 0, flag);
        gemm_mfma_k<1, 0, 0><<<gCKV, blk, 0, stream>>>(encoded, nullptr, ca_kv, oCKV,
            nullptr, 0, 0, Kb, nullptr, (int)NENC, 2 * DD, DD, 0, DD, NENC * DD, flag);
        attn_tile_k<0><<<attn_blocks, 256, 0, stream>>>(Qb, Kb, Vb, obh, obl, MM);
        gemm_mfma_k<2, 0, 0><<<gP, blk, 0, stream>>>(obh, obl, ca_o, oO,
            nullptr, 0, 0, Tb, nullptr, (int)NTOK, DD, DD, 0, 0, 0, flag);
        add_ln_k<<<NTOK, 256, 0, stream>>>(x, Tb, xh, xl, ln_g, oG + DD, ln_b, oG + DD, flag);
        // --- FFN ---
        gemm_mfma_k<2, 0, 1><<<gW1, blk, 0, stream>>>(xh, xl, ffn_w1, oW1,
            ffn_b1, oB1, 1, hbh, hbl, (int)NTOK, FF, DD, 1, 0, 0, flag);
        gemm_mfma_k<2, 0, 0><<<gP, blk, 0, stream>>>(hbh, hbl, ffn_w2, oW2,
            ffn_b2, oB2, 1, Tb, nullptr, (int)NTOK, DD, FF, 0, 0, 0, flag);
        add_ln_k<<<NTOK, 256, 0, stream>>>(x, Tb, xh, xl, ln_g, oG + 2 * DD, ln_b, oG + 2 * DD, flag);
    }
    // final norm + shared-embedding logits
    add_ln_k<<<NTOK, 256, 0, stream>>>(x, nullptr, xh, xl, fin_g, 0, fin_b, 0, flag);
    gemm_mfma_k<2, 1, 2><<<gOut, blk, 0, stream>>>(xh, xl, (const char*)input_embed, 0,
        (const char*)output_bias, 0, 1, d_out, nullptr, (int)NTOK, VV, DD, 0, 0, 0, flag);
}

// Round 2
// 3122.300 us; speedup vs baseline: 2.2341x; 2.2341x over previous
//
#include <hip/hip_runtime.h>
#include <hip/hip_bf16.h>

#define DD 256
#define HH 8
#define DH 32
#define SS 512
#define MM 1024
#define BB 16
#define FF 1024
#define LL 6
#define VV 3000

typedef __bf16 bf16x8 __attribute__((ext_vector_type(8)));
typedef float  f32x4  __attribute__((ext_vector_type(4)));

// Mixed-dtype load: bf==1 -> bf16, bf==0 -> fp32.
__device__ __forceinline__ float ldx(const void* p, size_t i, int bf) {
    if (bf) return __bfloat162float(((const __hip_bfloat16*)p)[i]);
    return ((const float*)p)[i];
}

// fp32 -> bf16 hi/lo split: v = hi + lo + O(2^-17 * v)
__device__ __forceinline__ void split1(float v, __bf16& h, __bf16& l) {
    h = (__bf16)v;
    l = (__bf16)(v - (float)h);
}

// dtype detector: writes 1 if buffer is bf16, 0 if fp32.
__global__ void detect_k(const unsigned int* __restrict__ w, int* __restrict__ flag) {
    int t = threadIdx.x;
    unsigned int v = w[t];
    int ok = 1;
#pragma unroll
    for (int h = 0; h < 2; ++h) {
        unsigned int hw = (v >> (16 * h)) & 0xFFFFu;
        unsigned int e = (hw >> 7) & 0xFFu;
        if (!((e >= 90u && e <= 140u) || (hw & 0x7FFFu) == 0u)) ok = 0;
    }
    __shared__ int allok;
    if (t == 0) allok = 1;
    __syncthreads();
    if (!ok) atomicAnd(&allok, 0);
    __syncthreads();
    if (t == 0) *flag = allok;
}

// x = input_embed[seq] + pos_embed ; also writes hi/lo split of x
__global__ void embed_k(const int* __restrict__ seq,
                        const void* __restrict__ emb,
                        const void* __restrict__ pos,
                        float* __restrict__ x,
                        __bf16* __restrict__ xh,
                        __bf16* __restrict__ xl,
                        const int* __restrict__ flagp) {
    int bf = *flagp;
    int row = blockIdx.x;           // b*512 + s
    int d = threadIdx.x;            // 0..255
    int s = row & (SS - 1);
    int b = row >> 9;
    int tok = seq[b * SS + s];
    float v = ldx(emb, (size_t)tok * DD + d, bf) + ldx(pos, (size_t)s * DD + d, bf);
    size_t idx = (size_t)row * DD + d;
    x[idx] = v;
    split1(v, xh[idx], xl[idx]);
}

// ---------------------------------------------------------------------------
// Split-bf16 MFMA GEMM.  C[M,N] = A[M,K] @ B[K,N] (+bias)(+relu)
//   AMODE 1: A is flag-dtype global (fp32/bf16), split in-kernel (encoded)
//   AMODE 2: A is pre-split pair (A = hi array, Al_ = lo array, bf16)
//   BTRANS 0: B row-major [K][N] weights; 1: B is [N][K] (embedding, guarded)
//   OUTMODE 0: fp32 C; 1: split pair C/C2 (bf16 hi/lo); 2: flag-dtype store
//   nsplit>0: B / C are nmat stacked [K][nsplit] / [M][nsplit] matrices.
// ---------------------------------------------------------------------------
template <int AMODE, int BTRANS, int OUTMODE>
__global__ __launch_bounds__(128, 2)
void gemm_mfma_k(const void* __restrict__ A, const void* __restrict__ Al_,
                 const char* __restrict__ Bbase, size_t boff,
                 const char* __restrict__ biasbase, size_t biasoff, int hasbias,
                 void* __restrict__ C, void* __restrict__ C2,
                 int M, int N, int K, int relu,
                 int nsplit, size_t cstride,
                 const int* __restrict__ flagp) {
    int bfw = *flagp;
    int esz = bfw ? 2 : 4;
    const char* Bw = Bbase + boff * esz;
    int t = threadIdx.x;
    int lane = t & 63;
    int wv = t >> 6;                 // wave id: rows wv*64..wv*64+63
    int n0 = blockIdx.x * 64;
    int m0 = blockIdx.y * 128;
    int ldb = N, ldc = N;
    float* Cf = (float*)C;
    if (nsplit) {
        int mat = n0 / nsplit;
        n0 -= mat * nsplit;
        Bw += (size_t)mat * K * nsplit * esz;
        Cf += (size_t)mat * cstride;
        ldb = ldc = nsplit;
    }

    __shared__ __align__(16) __bf16 Ah[128][32];
    __shared__ __align__(16) __bf16 Al[128][32];
    __shared__ __align__(16) __bf16 Bh[64][32];
    __shared__ __align__(16) __bf16 Bl[64][32];

    f32x4 acc[4][4] = {};
    int fr = lane & 15;              // frag row (A) / col (B,C)
    int fg = lane >> 4;              // k-group 0..3
    int t_alo = !(AMODE == 1 && bfw);   // A_lo term needed?
    int t_blo = !bfw;                   // B_lo term needed?

    for (int k0 = 0; k0 < K; k0 += 32) {
        // ---- stage A tile [128][32] ----
        if (AMODE == 2) {
            const __bf16* Ahg = (const __bf16*)A;
            const __bf16* Alg = (const __bf16*)Al_;
#pragma unroll
            for (int i = 0; i < 4; ++i) {
                int c = i * 128 + t;
                int row = c >> 2, kc = (c & 3) * 8;
                size_t g = (size_t)(m0 + row) * K + k0 + kc;
                *(bf16x8*)&Ah[row][kc] = *(const bf16x8*)(Ahg + g);
                *(bf16x8*)&Al[row][kc] = *(const bf16x8*)(Alg + g);
            }
        } else {  // AMODE==1: flag-dtype global, split in-kernel
#pragma unroll
            for (int i = 0; i < 8; ++i) {
                int row = i * 16 + (t >> 3);
                int kc = (t & 7) * 4;
                size_t g = (size_t)(m0 + row) * K + k0 + kc;
                float va[4];
                if (bfw) {
#pragma unroll
                    for (int j = 0; j < 4; ++j)
                        va[j] = __bfloat162float(((const __hip_bfloat16*)A)[g + j]);
                } else {
                    float4 f4 = *(const float4*)((const float*)A + g);
                    va[0] = f4.x; va[1] = f4.y; va[2] = f4.z; va[3] = f4.w;
                }
#pragma unroll
                for (int j = 0; j < 4; ++j)
                    split1(va[j], Ah[row][kc + j], Al[row][kc + j]);
            }
        }
        // ---- stage B tile -> Bs[n][k] swizzled ----
        if (BTRANS == 0) {
            int n = t & 63, g2 = t >> 6;
#pragma unroll
            for (int half = 0; half < 2; ++half) {
                int kb = g2 * 16 + half * 8;
                bf16x8 hv, lv;
#pragma unroll
                for (int i = 0; i < 8; ++i) {
                    float v = ldx(Bw, (size_t)(k0 + kb + i) * ldb + n0 + n, bfw);
                    __bf16 h, l; split1(v, h, l);
                    hv[i] = h; lv[i] = l;
                }
                int ke = kb ^ ((n & 3) << 3);
                *(bf16x8*)&Bh[n][ke] = hv;
                *(bf16x8*)&Bl[n][ke] = lv;
            }
        } else {  // B is [N][K] row-major (shared embedding), guard N
            int n = t >> 1, half = t & 1;
            int ok = (n0 + n) < N;
#pragma unroll
            for (int q = 0; q < 2; ++q) {
                int kb = half * 16 + q * 8;
                bf16x8 hv, lv;
#pragma unroll
                for (int i = 0; i < 8; ++i) {
                    float v = ok ? ldx(Bw, (size_t)(n0 + n) * K + k0 + kb + i, bfw) : 0.f;
                    __bf16 h, l; split1(v, h, l);
                    hv[i] = h; lv[i] = l;
                }
                int ke = kb ^ ((n & 3) << 3);
                *(bf16x8*)&Bh[n][ke] = hv;
                *(bf16x8*)&Bl[n][ke] = lv;
            }
        }
        __syncthreads();

        // ---- fragments + MFMA ----
        bf16x8 afh[4], afl[4], bgh[4], bgl[4];
#pragma unroll
        for (int f = 0; f < 4; ++f) {
            int ar = wv * 64 + f * 16 + fr;
            afh[f] = *(const bf16x8*)&Ah[ar][fg * 8];
            afl[f] = *(const bf16x8*)&Al[ar][fg * 8];
            int bn = f * 16 + fr;
            int ke = (fg * 8) ^ ((bn & 3) << 3);
            bgh[f] = *(const bf16x8*)&Bh[bn][ke];
            bgl[f] = *(const bf16x8*)&Bl[bn][ke];
        }
#pragma unroll
        for (int mf = 0; mf < 4; ++mf)
#pragma unroll
            for (int nf = 0; nf < 4; ++nf) {
                acc[mf][nf] = __builtin_amdgcn_mfma_f32_16x16x32_bf16(afh[mf], bgh[nf], acc[mf][nf], 0, 0, 0);
                if (t_alo)
                    acc[mf][nf] = __builtin_amdgcn_mfma_f32_16x16x32_bf16(afl[mf], bgh[nf], acc[mf][nf], 0, 0, 0);
                if (t_blo)
                    acc[mf][nf] = __builtin_amdgcn_mfma_f32_16x16x32_bf16(afh[mf], bgl[nf], acc[mf][nf], 0, 0, 0);
            }
        __syncthreads();
    }

    // ---- epilogue ----
    const char* biasp = biasbase + biasoff * esz;
#pragma unroll
    for (int mf = 0; mf < 4; ++mf)
#pragma unroll
        for (int nf = 0; nf < 4; ++nf)
#pragma unroll
            for (int r = 0; r < 4; ++r) {
                int row = m0 + wv * 64 + mf * 16 + fg * 4 + r;
                int col = n0 + nf * 16 + fr;
                float v = acc[mf][nf][r];
                if (OUTMODE == 2) {
                    if (col < N) {
                        v += ldx(biasp, col, bfw);
                        size_t oi = (size_t)row * N + col;
                        if (bfw) ((__hip_bfloat16*)C)[oi] = __float2bfloat16(v);
                        else     ((float*)C)[oi] = v;
                    }
                } else {
                    if (hasbias) v += ldx(biasp, col, bfw);
                    if (relu) v = fmaxf(v, 0.f);
                    size_t oi = (size_t)row * ldc + col;
                    if (OUTMODE == 1) {
                        __bf16 h, l; split1(v, h, l);
                        ((__bf16*)C)[oi]  = h;
                        ((__bf16*)C2)[oi] = l;
                    } else {
                        Cf[oi] = v;
                    }
                }
            }
}

// ---------------------------------------------------------------------------
// MFMA flash attention. Block = (b, h, 64 q-rows) -> 1024 blocks, 4 waves.
// Wave w owns q rows [w*16, w*16+16). Per 64-row K/V tile:
//   QK^T: S[16q][64k] = 4 subtiles x 3 split-MFMAs (qh*kh + ql*kh + qh*kl)
//   online softmax in C-layout regs (col=lane&15, row=(lane>>4)*4+r),
//     row-reduce via 4x shfl_xor over the 16-lane col group
//   P -> per-wave LDS (hi/lo) to convert C-layout -> A-fragment layout
//   PV: O[16q][32d] += 2 d-tiles x 2 k-chunks x 3 split-MFMAs, V staged
//     TRANSPOSED in LDS (V_lds[d][k], contraction dim contiguous).
// Pads chosen for min bank load: K stride 40 el (80B), V/P stride 72 el (144B).
// Q pre-scaled by 1/sqrt(32) before split.
// ---------------------------------------------------------------------------
template <int CAUSAL>
__global__ __launch_bounds__(256)
void attn_mfma_k(const float* __restrict__ Q,
                 const float* __restrict__ K,
                 const float* __restrict__ V,
                 __bf16* __restrict__ Oh,
                 __bf16* __restrict__ Ol,
                 int Sk) {
    __shared__ __align__(16) __bf16 Kh[64][40];
    __shared__ __align__(16) __bf16 Kl[64][40];
    __shared__ __align__(16) __bf16 Vh[32][72];
    __shared__ __align__(16) __bf16 Vl[32][72];
    __shared__ __align__(16) __bf16 Ph[4][16][72];
    __shared__ __align__(16) __bf16 Pl[4][16][72];

    int t = threadIdx.x;
    int lane = t & 63;
    int w = t >> 6;
    int l15 = lane & 15;
    int g = lane >> 4;

    int blk = blockIdx.x;           // (b*HH + h)*8 + qt
    int qt = blk & 7;
    int h  = (blk >> 3) & (HH - 1);
    int b  = blk >> 6;
    int q0 = qt * 64;

    const float scale = 0.17677669529663689f;  // 1/sqrt(32)

    // Q fragment (A-operand): row = l15, k(d) = g*8 + e. Pre-scale then split.
    bf16x8 qh_, ql_;
    {
        const float* qp = Q + ((size_t)(b * SS + q0 + w * 16 + l15)) * DD + h * 32 + g * 8;
        float4 qa = ((const float4*)qp)[0];
        float4 qb = ((const float4*)qp)[1];
        float qv[8] = {qa.x, qa.y, qa.z, qa.w, qb.x, qb.y, qb.z, qb.w};
#pragma unroll
        for (int j = 0; j < 8; ++j) {
            __bf16 hh, ll; split1(qv[j] * scale, hh, ll);
            qh_[j] = hh; ql_[j] = ll;
        }
    }

    f32x4 oacc[2] = {};
    float m_r[4] = {-1e30f, -1e30f, -1e30f, -1e30f};
    float l_r[4] = {0.f, 0.f, 0.f, 0.f};

    int ntiles = CAUSAL ? (qt + 1) : (Sk >> 6);

    for (int tt = 0; tt < ntiles; ++tt) {
        int j0 = tt * 64;
        // ---- stage K (row-major, pad 40) and V (transposed, pad 72) ----
        {
            int row = t >> 2, db = (t & 3) * 8;
            const float* kp = K + ((size_t)(b * Sk + j0 + row)) * DD + h * 32 + db;
            float4 k1 = ((const float4*)kp)[0];
            float4 k2 = ((const float4*)kp)[1];
            float kv[8] = {k1.x, k1.y, k1.z, k1.w, k2.x, k2.y, k2.z, k2.w};
            bf16x8 hv, lv;
#pragma unroll
            for (int j = 0; j < 8; ++j) { __bf16 hh, ll; split1(kv[j], hh, ll); hv[j] = hh; lv[j] = ll; }
            *(bf16x8*)&Kh[row][db] = hv;
            *(bf16x8*)&Kl[row][db] = lv;

            const float* vp = V + ((size_t)(b * Sk + j0 + row)) * DD + h * 32 + db;
            float4 v1 = ((const float4*)vp)[0];
            float4 v2 = ((const float4*)vp)[1];
            float vv[8] = {v1.x, v1.y, v1.z, v1.w, v2.x, v2.y, v2.z, v2.w};
#pragma unroll
            for (int j = 0; j < 8; ++j) {
                __bf16 hh, ll; split1(vv[j], hh, ll);
                Vh[db + j][row] = hh;
                Vl[db + j][row] = ll;
            }
        }
        __syncthreads();

        // ---- QK^T: S[16q][64k] per wave ----
        f32x4 s[4] = {};
#pragma unroll
        for (int kt = 0; kt < 4; ++kt) {
            bf16x8 kbh = *(const bf16x8*)&Kh[kt * 16 + l15][g * 8];
            bf16x8 kbl = *(const bf16x8*)&Kl[kt * 16 + l15][g * 8];
            s[kt] = __builtin_amdgcn_mfma_f32_16x16x32_bf16(qh_, kbh, s[kt], 0, 0, 0);
            s[kt] = __builtin_amdgcn_mfma_f32_16x16x32_bf16(ql_, kbh, s[kt], 0, 0, 0);
            s[kt] = __builtin_amdgcn_mfma_f32_16x16x32_bf16(qh_, kbl, s[kt], 0, 0, 0);
        }

        // ---- causal mask: only the diagonal tile needs it ----
        if (CAUSAL && tt == ntiles - 1) {
            int qa_ = q0 + w * 16 + g * 4;
#pragma unroll
            for (int kt = 0; kt < 4; ++kt)
#pragma unroll
                for (int r = 0; r < 4; ++r)
                    if (j0 + kt * 16 + l15 > qa_ + r) s[kt][r] = -1e30f;
        }

        // ---- online softmax (per q-row r), then P -> LDS split ----
        float al_r[4];
#pragma unroll
        for (int r = 0; r < 4; ++r) {
            float mx = fmaxf(fmaxf(s[0][r], s[1][r]), fmaxf(s[2][r], s[3][r]));
#pragma unroll
            for (int off = 1; off < 16; off <<= 1) mx = fmaxf(mx, __shfl_xor(mx, off));
            float mnew = fmaxf(m_r[r], mx);
            al_r[r] = __expf(m_r[r] - mnew);
            float ps = 0.f;
#pragma unroll
            for (int kt = 0; kt < 4; ++kt) {
                float p = __expf(s[kt][r] - mnew);
                s[kt][r] = p;
                ps += p;
            }
#pragma unroll
            for (int off = 1; off < 16; off <<= 1) ps += __shfl_xor(ps, off);
            l_r[r] = l_r[r] * al_r[r] + ps;
            m_r[r] = mnew;
        }
        // rescale O accumulators
#pragma unroll
        for (int dt = 0; dt < 2; ++dt)
#pragma unroll
            for (int r = 0; r < 4; ++r) oacc[dt][r] *= al_r[r];
        // write P (C-layout -> LDS rows)
#pragma unroll
        for (int kt = 0; kt < 4; ++kt)
#pragma unroll
            for (int r = 0; r < 4; ++r) {
                __bf16 hh, ll; split1(s[kt][r], hh, ll);
                Ph[w][g * 4 + r][kt * 16 + l15] = hh;
                Pl[w][g * 4 + r][kt * 16 + l15] = ll;
            }
        __syncthreads();

        // ---- PV: O[16q][32d] += P[16q][64k] @ V[64k][32d] ----
#pragma unroll
        for (int kc = 0; kc < 2; ++kc) {
            bf16x8 pa  = *(const bf16x8*)&Ph[w][l15][kc * 32 + g * 8];
            bf16x8 pal = *(const bf16x8*)&Pl[w][l15][kc * 32 + g * 8];
#pragma unroll
            for (int dt = 0; dt < 2; ++dt) {
                bf16x8 vb  = *(const bf16x8*)&Vh[dt * 16 + l15][kc * 32 + g * 8];
                bf16x8 vbl = *(const bf16x8*)&Vl[dt * 16 + l15][kc * 32 + g * 8];
                oacc[dt] = __builtin_amdgcn_mfma_f32_16x16x32_bf16(pa, vb, oacc[dt], 0, 0, 0);
                oacc[dt] = __builtin_amdgcn_mfma_f32_16x16x32_bf16(pal, vb, oacc[dt], 0, 0, 0);
                oacc[dt] = __builtin_amdgcn_mfma_f32_16x16x32_bf16(pa, vbl, oacc[dt], 0, 0, 0);
            }
        }
        __syncthreads();
    }

    // ---- epilogue: O / l, split-store ----
    float inv[4];
#pragma unroll
    for (int r = 0; r < 4; ++r) inv[r] = 1.f / l_r[r];
#pragma unroll
    for (int dt = 0; dt < 2; ++dt)
#pragma unroll
        for (int r = 0; r < 4; ++r) {
            float v = oacc[dt][r] * inv[r];
            size_t oi = ((size_t)(b * SS + q0 + w * 16 + g * 4 + r)) * DD + h * 32 + dt * 16 + l15;
            __bf16 hh, ll; split1(v, hh, ll);
            Oh[oi] = hh;
            Ol[oi] = ll;
        }
}

// x = LN(x + h); also writes hi/lo split of new x.
__global__ void add_ln_k(float* __restrict__ x,
                         const float* __restrict__ hbuf,
                         __bf16* __restrict__ xh,
                         __bf16* __restrict__ xl,
                         const char* __restrict__ gbase, size_t goff,
                         const char* __restrict__ bbase, size_t boff,
                         const int* __restrict__ flagp) {
    int bf = *flagp;
    const void* g = gbase + goff * (bf ? 2 : 4);
    const void* bb = bbase + boff * (bf ? 2 : 4);
    int row = blockIdx.x;
    int d = threadIdx.x;                 // 256 threads, one per element
    float v = x[(size_t)row * DD + d];
    if (hbuf) v += hbuf[(size_t)row * DD + d];
    float s = v, s2 = v * v;
#pragma unroll
    for (int off = 32; off > 0; off >>= 1) {
        s += __shfl_down(s, off);
        s2 += __shfl_down(s2, off);
    }
    __shared__ float sh[8];
    int w = d >> 6;
    if ((d & 63) == 0) { sh[w] = s; sh[4 + w] = s2; }
    __syncthreads();
    if (d == 0) {
        sh[0] = sh[0] + sh[1] + sh[2] + sh[3];
        sh[4] = sh[4] + sh[5] + sh[6] + sh[7];
    }
    __syncthreads();
    float mu = sh[0] * (1.f / DD);
    float var = fmaxf(sh[4] * (1.f / DD) - mu * mu, 0.f);
    float inv = rsqrtf(var + 1e-5f);
    float o = (v - mu) * inv * ldx(g, d, bf) + ldx(bb, d, bf);
    size_t idx = (size_t)row * DD + d;
    x[idx] = o;
    split1(o, xh[idx], xl[idx]);
}

extern "C" void kernel_launch(void* const* d_in, const int* in_sizes, int n_in,
                              void* d_out, int out_size, void* d_ws, size_t ws_size,
                              hipStream_t stream) {
    const void* encoded     = d_in[0];
    const int*  seq         = (const int*)d_in[1];
    const void* input_embed = d_in[2];
    const void* pos_embed   = d_in[3];
    const void* output_bias = d_in[4];
    const char* sa_qkv      = (const char*)d_in[5];
    const char* sa_o        = (const char*)d_in[6];
    const char* ca_q        = (const char*)d_in[7];
    const char* ca_kv       = (const char*)d_in[8];
    const char* ca_o        = (const char*)d_in[9];
    const char* ffn_w1      = (const char*)d_in[10];
    const char* ffn_b1      = (const char*)d_in[11];
    const char* ffn_w2      = (const char*)d_in[12];
    const char* ffn_b2      = (const char*)d_in[13];
    const char* ln_g        = (const char*)d_in[14];
    const char* ln_b        = (const char*)d_in[15];
    const char* fin_g       = (const char*)d_in[16];
    const char* fin_b       = (const char*)d_in[17];

    const size_t NTOK = (size_t)BB * SS;          // 8192
    const size_t NENC = (size_t)BB * MM;          // 16384

    // Workspace (~56 MiB):
    int*    flag = (int*)d_ws;
    float*  x  = (float*)d_ws + 64;               // 8 MiB
    __bf16* xh = (__bf16*)(x + NTOK * DD);        // 4 MiB
    __bf16* xl = xh + NTOK * DD;                  // 4 MiB
    float*  Qb = (float*)(xl + NTOK * DD);        // 8 MiB
    float*  Kb = Qb + NTOK * DD;                  // 16 MiB (cross K / FFN hidden hi)
    float*  Vb = Kb + NENC * DD;                  // 16 MiB (cross V / FFN hidden lo)
    // aliases (stream-ordered, lifetimes verified):
    float*  Tb  = Qb;                 // gemm temp after attention
    __bf16* obh = xh;                 // attn O split: xh/xl dead between
    __bf16* obl = xl;                 //   QKV-read and next add_ln write
    __bf16* hbh = (__bf16*)Kb;        // FFN hidden split (Kb/Vb dead post-attn)
    __bf16* hbl = (__bf16*)Vb;

    detect_k<<<1, 256, 0, stream>>>((const unsigned int*)input_embed, flag);
    embed_k<<<NTOK, 256, 0, stream>>>(seq, input_embed, pos_embed, x, xh, xl, flag);

    dim3 blk(128);
    dim3 gQKV(12, 64);                 // fused QKV, N=768 as 3x[256]
    dim3 gP(4, 64);                    // N=256, M=8192 projections
    dim3 gCKV(8, 128);                 // fused cross K/V, N=512, M=16384
    dim3 gW1(16, 64);                  // N=1024
    dim3 gOut(47, 64);                 // N=3000 (guarded)
    int attn_blocks = BB * HH * (SS / 64);        // 1024

    for (int l = 0; l < LL; ++l) {
        size_t oQKV = (size_t)l * 3 * DD * DD;
        size_t oO   = (size_t)l * DD * DD;
        size_t oCKV = (size_t)l * 2 * DD * DD;
        size_t oW1  = (size_t)l * DD * FF;
        size_t oB1  = (size_t)l * FF;
        size_t oW2  = (size_t)l * FF * DD;
        size_t oB2  = (size_t)l * DD;
        size_t oG   = (size_t)l * 3 * DD;

        // --- self attention: fused QKV (Q->Qb, K->Qb+2M=Kb, V->Qb+4M) ---
        gemm_mfma_k<2, 0, 0><<<gQKV, blk, 0, stream>>>(xh, xl, sa_qkv, oQKV,
            nullptr, 0, 0, Qb, nullptr, (int)NTOK, 3 * DD, DD, 0, DD, NTOK * DD, flag);
        attn_mfma_k<1><<<attn_blocks, 256, 0, stream>>>(Qb, Kb, Kb + NTOK * DD, obh, obl, SS);
        gemm_mfma_k<2, 0, 0><<<gP, blk, 0, stream>>>(obh, obl, sa_o, oO,
            nullptr, 0, 0, Tb, nullptr, (int)NTOK, DD, DD, 0, 0, 0, flag);
        add_ln_k<<<NTOK, 256, 0, stream>>>(x, Tb, xh, xl, ln_g, oG, ln_b, oG, flag);
        // --- cross attention ---
        gemm_mfma_k<2, 0, 0><<<gP, blk, 0, stream>>>(xh, xl, ca_q, oO,
            nullptr, 0, 0, Qb, nullptr, (int)NTOK, DD, DD, 0, 0, 0, flag);
        gemm_mfma_k<1, 0, 0><<<gCKV, blk, 0, stream>>>(encoded, nullptr, ca_kv, oCKV,
            nullptr, 0, 0, Kb, nullptr, (int)NENC, 2 * DD, DD, 0, DD, NENC * DD, flag);
        attn_mfma_k<0><<<attn_blocks, 256, 0, stream>>>(Qb, Kb, Vb, obh, obl, MM);
        gemm_mfma_k<2, 0, 0><<<gP, blk, 0, stream>>>(obh, obl, ca_o, oO,
            nullptr, 0, 0, Tb, nullptr, (int)NTOK, DD, DD, 0, 0, 0, flag);
        add_ln_k<<<NTOK, 256, 0, stream>>>(x, Tb, xh, xl, ln_g, oG + DD, ln_b, oG + DD, flag);
        // --- FFN ---
        gemm_mfma_k<2, 0, 1><<<gW1, blk, 0, stream>>>(xh, xl, ffn_w1, oW1,
            ffn_b1, oB1, 1, hbh, hbl, (int)NTOK, FF, DD, 1, 0, 0, flag);
        gemm_mfma_k<2, 0, 0><<<gP, blk, 0, stream>>>(hbh, hbl, ffn_w2, oW2,
            ffn_b2, oB2, 1, Tb, nullptr, (int)NTOK, DD, FF, 0, 0, 0, flag);
        add_ln_k<<<NTOK, 256, 0, stream>>>(x, Tb, xh, xl, ln_g, oG + 2 * DD, ln_b, oG + 2 * DD, flag);
    }
    // final norm + shared-embedding logits
    add_ln_k<<<NTOK, 256, 0, stream>>>(x, nullptr, xh, xl, fin_g, 0, fin_b, 0, flag);
    gemm_mfma_k<2, 1, 2><<<gOut, blk, 0, stream>>>(xh, xl, (const char*)input_embed, 0,
        (const char*)output_bias, 0, 1, d_out, nullptr, (int)NTOK, VV, DD, 0, 0, 0, flag);
}

// Round 4
// 2168.502 us; speedup vs baseline: 3.2167x; 1.4398x over previous
//
#include <hip/hip_runtime.h>
#include <hip/hip_bf16.h>

#define DD 256
#define HH 8
#define DH 32
#define SS 512
#define MM 1024
#define BB 16
#define FF 1024
#define LL 6
#define VV 3000

typedef __bf16 bf16x8 __attribute__((ext_vector_type(8)));
typedef float  f32x4  __attribute__((ext_vector_type(4)));

// Wt layout offsets (elements). All matrices stored [N][K] bf16 hi/lo pairs.
#define W_QKV0 0u
#define W_SAO0 1179648u
#define W_CAQ0 1572864u
#define W_CKV0 1966080u
#define W_CAO0 2752512u
#define W_W10  3145728u
#define W_W20  4718592u
#define W_EMB0 6291456u
#define W_TOT  7061504u   // 6291456 + 3008*256

// Mixed-dtype load: bf==1 -> bf16, bf==0 -> fp32.
__device__ __forceinline__ float ldx(const void* p, size_t i, int bf) {
    if (bf) return __bfloat162float(((const __hip_bfloat16*)p)[i]);
    return ((const float*)p)[i];
}

// fp32 -> bf16 hi/lo split: v = hi + lo + O(2^-17 * v)
__device__ __forceinline__ void split1(float v, __bf16& h, __bf16& l) {
    h = (__bf16)v;
    l = (__bf16)(v - (float)h);
}

// dtype detector: writes 1 if buffer is bf16, 0 if fp32.
__global__ void detect_k(const unsigned int* __restrict__ w, int* __restrict__ flag) {
    int t = threadIdx.x;
    unsigned int v = w[t];
    int ok = 1;
#pragma unroll
    for (int h = 0; h < 2; ++h) {
        unsigned int hw = (v >> (16 * h)) & 0xFFFFu;
        unsigned int e = (hw >> 7) & 0xFFu;
        if (!((e >= 90u && e <= 140u) || (hw & 0x7FFFu) == 0u)) ok = 0;
    }
    __shared__ int allok;
    if (t == 0) allok = 1;
    __syncthreads();
    if (!ok) atomicAnd(&allok, 0);
    __syncthreads();
    if (t == 0) *flag = allok;
}

// One-time: transpose+split all layer weights into [N][K] bf16 hi/lo pairs.
// Grid 1536 blocks (256/layer), block 256. LDS 64x64 tile transpose.
__global__ __launch_bounds__(256)
void wsplit_k(const void* __restrict__ sa_qkv, const void* __restrict__ sa_o,
              const void* __restrict__ ca_q, const void* __restrict__ ca_kv,
              const void* __restrict__ ca_o, const void* __restrict__ w1,
              const void* __restrict__ w2,
              __bf16* __restrict__ Wh, __bf16* __restrict__ Wl,
              const int* __restrict__ flagp) {
    int bfw = *flagp;
    __shared__ float tile[64][65];
    int blk = blockIdx.x;
    int l = blk >> 8, r = blk & 255;
    const void* src; size_t soff, doff; int K_, N_, ti;
    if (r < 48)       { src = sa_qkv; int j = r >> 4; ti = r & 15;
                        soff = (size_t)(l * 3 + j) * 65536; doff = W_QKV0 + soff; K_ = 256; N_ = 256; }
    else if (r < 64)  { src = sa_o;  ti = r - 48;  soff = (size_t)l * 65536; doff = W_SAO0 + soff; K_ = 256; N_ = 256; }
    else if (r < 80)  { src = ca_q;  ti = r - 64;  soff = (size_t)l * 65536; doff = W_CAQ0 + soff; K_ = 256; N_ = 256; }
    else if (r < 112) { src = ca_kv; int j = (r - 80) >> 4; ti = (r - 80) & 15;
                        soff = (size_t)(l * 2 + j) * 65536; doff = W_CKV0 + soff; K_ = 256; N_ = 256; }
    else if (r < 128) { src = ca_o;  ti = r - 112; soff = (size_t)l * 65536; doff = W_CAO0 + soff; K_ = 256; N_ = 256; }
    else if (r < 192) { src = w1;    ti = r - 128; soff = (size_t)l * 262144; doff = W_W10 + soff; K_ = 256; N_ = 1024; }
    else              { src = w2;    ti = r - 192; soff = (size_t)l * 262144; doff = W_W20 + soff; K_ = 1024; N_ = 256; }
    int ntil = N_ >> 6;
    int kt = ti / ntil, nt = ti % ntil;
    int k0 = kt * 64, n0 = nt * 64;
    int t = threadIdx.x;
#pragma unroll
    for (int rr = 0; rr < 16; ++rr) {
        int kk = rr * 4 + (t >> 6), nn = t & 63;
        tile[kk][nn] = ldx(src, soff + (size_t)(k0 + kk) * N_ + n0 + nn, bfw);
    }
    __syncthreads();
#pragma unroll
    for (int rr = 0; rr < 16; ++rr) {
        int nn = rr * 4 + (t >> 6), kk = t & 63;
        float v = tile[kk][nn];
        size_t o = doff + (size_t)(n0 + nn) * K_ + k0 + kk;
        split1(v, Wh[o], Wl[o]);
    }
}

// One-time: split shared embedding [V][D] (already n-major); pad rows V..3007 with 0.
__global__ void embsplit_k(const void* __restrict__ emb,
                           __bf16* __restrict__ Wh, __bf16* __restrict__ Wl,
                           const int* __restrict__ flagp) {
    int bfw = *flagp;
    int row = blockIdx.x;           // 0..3007
    int d = threadIdx.x;
    float v = (row < VV) ? ldx(emb, (size_t)row * DD + d, bfw) : 0.f;
    size_t o = W_EMB0 + (size_t)row * DD + d;
    split1(v, Wh[o], Wl[o]);
}

// x = input_embed[seq] + pos_embed ; also writes hi/lo split of x
__global__ void embed_k(const int* __restrict__ seq,
                        const void* __restrict__ emb,
                        const void* __restrict__ pos,
                        float* __restrict__ x,
                        __bf16* __restrict__ xh,
                        __bf16* __restrict__ xl,
                        const int* __restrict__ flagp) {
    int bf = *flagp;
    int row = blockIdx.x;
    int d = threadIdx.x;
    int s = row & (SS - 1);
    int b = row >> 9;
    int tok = seq[b * SS + s];
    float v = ldx(emb, (size_t)tok * DD + d, bf) + ldx(pos, (size_t)s * DD + d, bf);
    size_t idx = (size_t)row * DD + d;
    x[idx] = v;
    split1(v, xh[idx], xl[idx]);
}

// ---------------------------------------------------------------------------
// Split-bf16 MFMA GEMM.  C[M,N] = A[M,K] @ B[K,N] (+bias)(+relu)
//   B: pre-split [N][K] bf16 hi/lo pairs at Wh/Wl + boff (elements).
//   AMODE 1: A is flag-dtype global, split in-kernel (encoded)
//   AMODE 2: A is pre-split pair (Ah_/Al_ bf16)
//   OUTMODE 0: fp32 C; 1: split pair C/C2; 2: flag-dtype store, col<N guard
//   nsplit>0: B rows / C are stacked mats. B uses GLOBAL n (rows stacked
//   contiguously); C uses within-mat n and is advanced by mat*cstride.
// Tile BM=64 BN=64 BK=32, 128 thr = 2 waves, wave 32x64 (2x4 frags 16x16x32).
// ---------------------------------------------------------------------------
template <int AMODE, int OUTMODE>
__global__ __launch_bounds__(128, 3)
void gemm_mfma_k(const void* __restrict__ A, const void* __restrict__ Al_,
                 const __bf16* __restrict__ Wh, const __bf16* __restrict__ Wl, size_t boff,
                 const char* __restrict__ biasbase, size_t biasoff, int hasbias,
                 void* __restrict__ C, void* __restrict__ C2,
                 int M, int N, int K, int relu,
                 int nsplit, size_t cstride,
                 const int* __restrict__ flagp) {
    int bfw = *flagp;
    const __bf16* Bh_g = Wh + boff;
    const __bf16* Bl_g = Wl + boff;
    int t = threadIdx.x;
    int lane = t & 63;
    int wv = t >> 6;
    int nB0 = blockIdx.x * 64;       // GLOBAL n for B loads (stacked rows)
    int n0 = nB0;                    // within-mat n for C addressing
    int m0 = blockIdx.y * 64;
    int ldc = N;
    float* Cf = (float*)C;
    __bf16* Ch = (__bf16*)C;
    __bf16* Cl2 = (__bf16*)C2;
    if (nsplit) {
        int mat = n0 / nsplit;
        n0 -= mat * nsplit;
        Cf  += (size_t)mat * cstride;
        Ch  += (size_t)mat * cstride;
        Cl2 += (size_t)mat * cstride;
        ldc = nsplit;
    }

    __shared__ __align__(16) __bf16 Ah[64][32];
    __shared__ __align__(16) __bf16 Al[64][32];
    __shared__ __align__(16) __bf16 Bh[64][32];
    __shared__ __align__(16) __bf16 Bl[64][32];

    f32x4 acc[2][4] = {};
    int fr = lane & 15;
    int fg = lane >> 4;
    int t_alo = !(AMODE == 1 && bfw);
    int t_blo = !bfw;

    int ar_ = (t >> 2), ac_ = (t & 3) * 8;
    int bn_ = (t >> 1), bk_ = (t & 1) * 16;

    bf16x8 pah[2], pal[2], pbh[2], pbl[2];
    float  paf[2][8];

    auto loadA = [&](int k0) {
#pragma unroll
        for (int i = 0; i < 2; ++i) {
            size_t g = (size_t)(m0 + i * 32 + ar_) * K + k0 + ac_;
            if (AMODE == 2) {
                pah[i] = *(const bf16x8*)((const __bf16*)A + g);
                pal[i] = *(const bf16x8*)((const __bf16*)Al_ + g);
            } else {
                if (bfw) {
#pragma unroll
                    for (int j = 0; j < 8; ++j)
                        paf[i][j] = __bfloat162float(((const __hip_bfloat16*)A)[g + j]);
                } else {
                    float4 f1 = *(const float4*)((const float*)A + g);
                    float4 f2 = *(const float4*)((const float*)A + g + 4);
                    paf[i][0] = f1.x; paf[i][1] = f1.y; paf[i][2] = f1.z; paf[i][3] = f1.w;
                    paf[i][4] = f2.x; paf[i][5] = f2.y; paf[i][6] = f2.z; paf[i][7] = f2.w;
                }
            }
        }
    };
    auto loadB = [&](int k0) {
        size_t g = (size_t)(nB0 + bn_) * K + k0 + bk_;   // GLOBAL n
        pbh[0] = *(const bf16x8*)(Bh_g + g);
        pbh[1] = *(const bf16x8*)(Bh_g + g + 8);
        pbl[0] = *(const bf16x8*)(Bl_g + g);
        pbl[1] = *(const bf16x8*)(Bl_g + g + 8);
    };
    auto writeLDS = [&]() {
#pragma unroll
        for (int i = 0; i < 2; ++i) {
            int row = i * 32 + ar_;
            if (AMODE == 2) {
                *(bf16x8*)&Ah[row][ac_] = pah[i];
                *(bf16x8*)&Al[row][ac_] = pal[i];
            } else {
                bf16x8 hv, lv;
#pragma unroll
                for (int j = 0; j < 8; ++j) { __bf16 h, l; split1(paf[i][j], h, l); hv[j] = h; lv[j] = l; }
                *(bf16x8*)&Ah[row][ac_] = hv;
                *(bf16x8*)&Al[row][ac_] = lv;
            }
        }
        *(bf16x8*)&Bh[bn_][bk_]     = pbh[0];
        *(bf16x8*)&Bh[bn_][bk_ + 8] = pbh[1];
        *(bf16x8*)&Bl[bn_][bk_]     = pbl[0];
        *(bf16x8*)&Bl[bn_][bk_ + 8] = pbl[1];
    };

    loadA(0); loadB(0);
    for (int k0 = 0; k0 < K; k0 += 32) {
        writeLDS();
        __syncthreads();
        if (k0 + 32 < K) { loadA(k0 + 32); loadB(k0 + 32); }

        bf16x8 afh[2], afl[2], bgh[4], bgl[4];
#pragma unroll
        for (int f = 0; f < 2; ++f) {
            int ar = wv * 32 + f * 16 + fr;
            afh[f] = *(const bf16x8*)&Ah[ar][fg * 8];
            afl[f] = *(const bf16x8*)&Al[ar][fg * 8];
        }
#pragma unroll
        for (int f = 0; f < 4; ++f) {
            bgh[f] = *(const bf16x8*)&Bh[f * 16 + fr][fg * 8];
            bgl[f] = *(const bf16x8*)&Bl[f * 16 + fr][fg * 8];
        }
#pragma unroll
        for (int mf = 0; mf < 2; ++mf)
#pragma unroll
            for (int nf = 0; nf < 4; ++nf) {
                acc[mf][nf] = __builtin_amdgcn_mfma_f32_16x16x32_bf16(afh[mf], bgh[nf], acc[mf][nf], 0, 0, 0);
                if (t_alo)
                    acc[mf][nf] = __builtin_amdgcn_mfma_f32_16x16x32_bf16(afl[mf], bgh[nf], acc[mf][nf], 0, 0, 0);
                if (t_blo)
                    acc[mf][nf] = __builtin_amdgcn_mfma_f32_16x16x32_bf16(afh[mf], bgl[nf], acc[mf][nf], 0, 0, 0);
            }
        __syncthreads();
    }

    const char* biasp = biasbase + biasoff * (bfw ? 2 : 4);
#pragma unroll
    for (int mf = 0; mf < 2; ++mf)
#pragma unroll
        for (int nf = 0; nf < 4; ++nf)
#pragma unroll
            for (int r = 0; r < 4; ++r) {
                int row = m0 + wv * 32 + mf * 16 + fg * 4 + r;
                int col = n0 + nf * 16 + fr;
                float v = acc[mf][nf][r];
                if (OUTMODE == 2) {
                    if (col < N) {
                        v += ldx(biasp, col, bfw);
                        size_t oi = (size_t)row * N + col;
                        if (bfw) ((__hip_bfloat16*)C)[oi] = __float2bfloat16(v);
                        else     ((float*)C)[oi] = v;
                    }
                } else {
                    if (hasbias) v += ldx(biasp, col, bfw);
                    if (relu) v = fmaxf(v, 0.f);
                    size_t oi = (size_t)row * ldc + col;
                    if (OUTMODE == 1) {
                        __bf16 h, l; split1(v, h, l);
                        Ch[oi]  = h;
                        Cl2[oi] = l;
                    } else {
                        Cf[oi] = v;
                    }
                }
            }
}

// ---------------------------------------------------------------------------
// MFMA flash attention on pre-split bf16 pairs. Block = (b,h,64 q) -> 1024
// blocks, 4 waves; wave owns 16 q-rows. K/V staging = pure pair copies.
// ---------------------------------------------------------------------------
template <int CAUSAL>
__global__ __launch_bounds__(256)
void attn_mfma_k(const __bf16* __restrict__ Qh_g, const __bf16* __restrict__ Ql_g,
                 const __bf16* __restrict__ Kh_g, const __bf16* __restrict__ Kl_g,
                 const __bf16* __restrict__ Vh_g, const __bf16* __restrict__ Vl_g,
                 __bf16* __restrict__ Oh, __bf16* __restrict__ Ol,
                 int Sk) {
    __shared__ __align__(16) __bf16 Kh[64][40];
    __shared__ __align__(16) __bf16 Kl[64][40];
    __shared__ __align__(16) __bf16 Vh[32][72];
    __shared__ __align__(16) __bf16 Vl[32][72];
    __shared__ __align__(16) __bf16 Ph[4][16][72];
    __shared__ __align__(16) __bf16 Pl[4][16][72];

    int t = threadIdx.x;
    int lane = t & 63;
    int w = t >> 6;
    int l15 = lane & 15;
    int g = lane >> 4;

    int blk = blockIdx.x;           // (b*HH + h)*8 + qt
    int qt = blk & 7;
    int h  = (blk >> 3) & (HH - 1);
    int b  = blk >> 6;
    int q0 = qt * 64;

    const float scale = 0.17677669529663689f;  // 1/sqrt(32)

    // Q fragment: reconstruct fp32 from pair, pre-scale, re-split.
    bf16x8 qh_, ql_;
    {
        size_t qi = ((size_t)(b * SS + q0 + w * 16 + l15)) * DD + h * 32 + g * 8;
        bf16x8 qh8 = *(const bf16x8*)(Qh_g + qi);
        bf16x8 ql8 = *(const bf16x8*)(Ql_g + qi);
#pragma unroll
        for (int j = 0; j < 8; ++j) {
            float v = ((float)qh8[j] + (float)ql8[j]) * scale;
            __bf16 hh, ll; split1(v, hh, ll);
            qh_[j] = hh; ql_[j] = ll;
        }
    }

    f32x4 oacc[2] = {};
    float m_r[4] = {-1e30f, -1e30f, -1e30f, -1e30f};
    float l_r[4] = {0.f, 0.f, 0.f, 0.f};

    int ntiles = CAUSAL ? (qt + 1) : (Sk >> 6);

    for (int tt = 0; tt < ntiles; ++tt) {
        int j0 = tt * 64;
        // ---- stage K (pair copy) and V (pair transpose) ----
        {
            int row = t >> 2, db = (t & 3) * 8;
            size_t gi = ((size_t)(b * Sk + j0 + row)) * DD + h * 32 + db;
            *(bf16x8*)&Kh[row][db] = *(const bf16x8*)(Kh_g + gi);
            *(bf16x8*)&Kl[row][db] = *(const bf16x8*)(Kl_g + gi);
            bf16x8 vh8 = *(const bf16x8*)(Vh_g + gi);
            bf16x8 vl8 = *(const bf16x8*)(Vl_g + gi);
#pragma unroll
            for (int j = 0; j < 8; ++j) {
                Vh[db + j][row] = vh8[j];
                Vl[db + j][row] = vl8[j];
            }
        }
        __syncthreads();

        // ---- QK^T: S[16q][64k] per wave ----
        f32x4 s[4] = {};
#pragma unroll
        for (int kt = 0; kt < 4; ++kt) {
            bf16x8 kbh = *(const bf16x8*)&Kh[kt * 16 + l15][g * 8];
            bf16x8 kbl = *(const bf16x8*)&Kl[kt * 16 + l15][g * 8];
            s[kt] = __builtin_amdgcn_mfma_f32_16x16x32_bf16(qh_, kbh, s[kt], 0, 0, 0);
            s[kt] = __builtin_amdgcn_mfma_f32_16x16x32_bf16(ql_, kbh, s[kt], 0, 0, 0);
            s[kt] = __builtin_amdgcn_mfma_f32_16x16x32_bf16(qh_, kbl, s[kt], 0, 0, 0);
        }

        if (CAUSAL && tt == ntiles - 1) {
            int qa_ = q0 + w * 16 + g * 4;
#pragma unroll
            for (int kt = 0; kt < 4; ++kt)
#pragma unroll
                for (int r = 0; r < 4; ++r)
                    if (j0 + kt * 16 + l15 > qa_ + r) s[kt][r] = -1e30f;
        }

        // ---- online softmax ----
        float al_r[4];
#pragma unroll
        for (int r = 0; r < 4; ++r) {
            float mx = fmaxf(fmaxf(s[0][r], s[1][r]), fmaxf(s[2][r], s[3][r]));
#pragma unroll
            for (int off = 1; off < 16; off <<= 1) mx = fmaxf(mx, __shfl_xor(mx, off));
            float mnew = fmaxf(m_r[r], mx);
            al_r[r] = __expf(m_r[r] - mnew);
            float ps = 0.f;
#pragma unroll
            for (int kt = 0; kt < 4; ++kt) {
                float p = __expf(s[kt][r] - mnew);
                s[kt][r] = p;
                ps += p;
            }
#pragma unroll
            for (int off = 1; off < 16; off <<= 1) ps += __shfl_xor(ps, off);
            l_r[r] = l_r[r] * al_r[r] + ps;
            m_r[r] = mnew;
        }
#pragma unroll
        for (int dt = 0; dt < 2; ++dt)
#pragma unroll
            for (int r = 0; r < 4; ++r) oacc[dt][r] *= al_r[r];
#pragma unroll
        for (int kt = 0; kt < 4; ++kt)
#pragma unroll
            for (int r = 0; r < 4; ++r) {
                __bf16 hh, ll; split1(s[kt][r], hh, ll);
                Ph[w][g * 4 + r][kt * 16 + l15] = hh;
                Pl[w][g * 4 + r][kt * 16 + l15] = ll;
            }
        __syncthreads();

        // ---- PV ----
#pragma unroll
        for (int kc = 0; kc < 2; ++kc) {
            bf16x8 pa  = *(const bf16x8*)&Ph[w][l15][kc * 32 + g * 8];
            bf16x8 pal = *(const bf16x8*)&Pl[w][l15][kc * 32 + g * 8];
#pragma unroll
            for (int dt = 0; dt < 2; ++dt) {
                bf16x8 vb  = *(const bf16x8*)&Vh[dt * 16 + l15][kc * 32 + g * 8];
                bf16x8 vbl = *(const bf16x8*)&Vl[dt * 16 + l15][kc * 32 + g * 8];
                oacc[dt] = __builtin_amdgcn_mfma_f32_16x16x32_bf16(pa, vb, oacc[dt], 0, 0, 0);
                oacc[dt] = __builtin_amdgcn_mfma_f32_16x16x32_bf16(pal, vb, oacc[dt], 0, 0, 0);
                oacc[dt] = __builtin_amdgcn_mfma_f32_16x16x32_bf16(pa, vbl, oacc[dt], 0, 0, 0);
            }
        }
        __syncthreads();
    }

    float inv[4];
#pragma unroll
    for (int r = 0; r < 4; ++r) inv[r] = 1.f / l_r[r];
#pragma unroll
    for (int dt = 0; dt < 2; ++dt)
#pragma unroll
        for (int r = 0; r < 4; ++r) {
            float v = oacc[dt][r] * inv[r];
            size_t oi = ((size_t)(b * SS + q0 + w * 16 + g * 4 + r)) * DD + h * 32 + dt * 16 + l15;
            __bf16 hh, ll; split1(v, hh, ll);
            Oh[oi] = hh;
            Ol[oi] = ll;
        }
}

// x = LN(x + h); also writes hi/lo split of new x.
__global__ void add_ln_k(float* __restrict__ x,
                         const float* __restrict__ hbuf,
                         __bf16* __restrict__ xh,
                         __bf16* __restrict__ xl,
                         const char* __restrict__ gbase, size_t goff,
                         const char* __restrict__ bbase, size_t boff,
                         const int* __restrict__ flagp) {
    int bf = *flagp;
    const void* g = gbase + goff * (bf ? 2 : 4);
    const void* bb = bbase + boff * (bf ? 2 : 4);
    int row = blockIdx.x;
    int d = threadIdx.x;
    float v = x[(size_t)row * DD + d];
    if (hbuf) v += hbuf[(size_t)row * DD + d];
    float s = v, s2 = v * v;
#pragma unroll
    for (int off = 32; off > 0; off >>= 1) {
        s += __shfl_down(s, off);
        s2 += __shfl_down(s2, off);
    }
    __shared__ float sh[8];
    int w = d >> 6;
    if ((d & 63) == 0) { sh[w] = s; sh[4 + w] = s2; }
    __syncthreads();
    if (d == 0) {
        sh[0] = sh[0] + sh[1] + sh[2] + sh[3];
        sh[4] = sh[4] + sh[5] + sh[6] + sh[7];
    }
    __syncthreads();
    float mu = sh[0] * (1.f / DD);
    float var = fmaxf(sh[4] * (1.f / DD) - mu * mu, 0.f);
    float inv = rsqrtf(var + 1e-5f);
    float o = (v - mu) * inv * ldx(g, d, bf) + ldx(bb, d, bf);
    size_t idx = (size_t)row * DD + d;
    x[idx] = o;
    split1(o, xh[idx], xl[idx]);
}

extern "C" void kernel_launch(void* const* d_in, const int* in_sizes, int n_in,
                              void* d_out, int out_size, void* d_ws, size_t ws_size,
                              hipStream_t stream) {
    const void* encoded     = d_in[0];
    const int*  seq         = (const int*)d_in[1];
    const void* input_embed = d_in[2];
    const void* pos_embed   = d_in[3];
    const void* output_bias = d_in[4];
    const void* sa_qkv      = d_in[5];
    const void* sa_o        = d_in[6];
    const void* ca_q        = d_in[7];
    const void* ca_kv       = d_in[8];
    const void* ca_o        = d_in[9];
    const void* ffn_w1      = d_in[10];
    const char* ffn_b1      = (const char*)d_in[11];
    const void* ffn_w2      = d_in[12];
    const char* ffn_b2      = (const char*)d_in[13];
    const char* ln_g        = (const char*)d_in[14];
    const char* ln_b        = (const char*)d_in[15];
    const char* fin_g       = (const char*)d_in[16];
    const char* fin_b       = (const char*)d_in[17];

    const size_t NTOK = (size_t)BB * SS;          // 8192
    const size_t NENC = (size_t)BB * MM;          // 16384

    // Workspace layout (~99 MiB)
    char* p = (char*)d_ws;
    int*    flag = (int*)p;            p += 256;
    float*  x    = (float*)p;          p += NTOK * DD * 4;       // 8 MiB
    __bf16* xh   = (__bf16*)p;         p += NTOK * DD * 2;       // 4 MiB
    __bf16* xl   = (__bf16*)p;         p += NTOK * DD * 2;       // 4 MiB
    __bf16* SAh  = (__bf16*)p;         p += 3 * NTOK * DD * 2;   // 12 MiB (Q,K,V self)
    __bf16* SAl  = (__bf16*)p;         p += 3 * NTOK * DD * 2;   // 12 MiB
    __bf16* CKh  = (__bf16*)p;         p += 2 * NENC * DD * 2;   // 16 MiB (cross K,V / FFN H)
    __bf16* CKl  = (__bf16*)p;         p += 2 * NENC * DD * 2;   // 16 MiB
    __bf16* Wh   = (__bf16*)p;         p += (size_t)W_TOT * 2;   // 13.5 MiB
    __bf16* Wl   = (__bf16*)p;         p += (size_t)W_TOT * 2;   // 13.5 MiB
    // aliases (lifetimes verified):
    float*  Tb = (float*)(SAh + NTOK * DD);   // 8 MiB in dead self-K/V hi space
    __bf16* Qh = SAh;  __bf16* Ql = SAl;      // self Q and cross Q
    __bf16* Oh = xh;   __bf16* Ol = xl;       // attn O (xh/xl dead in between)
    __bf16* Hh = CKh;  __bf16* Hl = CKl;      // FFN hidden pairs

    detect_k<<<1, 256, 0, stream>>>((const unsigned int*)input_embed, flag);
    wsplit_k<<<1536, 256, 0, stream>>>(sa_qkv, sa_o, ca_q, ca_kv, ca_o,
                                       ffn_w1, ffn_w2, Wh, Wl, flag);
    embsplit_k<<<3008, 256, 0, stream>>>(input_embed, Wh, Wl, flag);
    embed_k<<<NTOK, 256, 0, stream>>>(seq, input_embed, pos_embed, x, xh, xl, flag);

    dim3 blk(128);
    dim3 gQKV(12, 128);                // N=768 (3 mats), M=8192
    dim3 gP(4, 128);                   // N=256, M=8192
    dim3 gCKV(8, 256);                 // N=512 (2 mats), M=16384
    dim3 gW1(16, 128);                 // N=1024, M=8192
    dim3 gOut(47, 128);                // N=3000 (guarded), M=8192
    int attn_blocks = BB * HH * (SS / 64);   // 1024

    for (int l = 0; l < LL; ++l) {
        size_t oQKV = W_QKV0 + (size_t)l * 3 * 65536;
        size_t oSAO = W_SAO0 + (size_t)l * 65536;
        size_t oCAQ = W_CAQ0 + (size_t)l * 65536;
        size_t oCKV = W_CKV0 + (size_t)l * 2 * 65536;
        size_t oCAO = W_CAO0 + (size_t)l * 65536;
        size_t oW1  = W_W10  + (size_t)l * 262144;
        size_t oW2  = W_W20  + (size_t)l * 262144;
        size_t oB1  = (size_t)l * FF;
        size_t oB2  = (size_t)l * DD;
        size_t oG   = (size_t)l * 3 * DD;

        // --- self attention ---
        gemm_mfma_k<2, 1><<<gQKV, blk, 0, stream>>>(xh, xl, Wh, Wl, oQKV,
            nullptr, 0, 0, SAh, SAl, (int)NTOK, 3 * DD, DD, 0, DD, NTOK * DD, flag);
        attn_mfma_k<1><<<attn_blocks, 256, 0, stream>>>(Qh, Ql,
            SAh + NTOK * DD, SAl + NTOK * DD, SAh + 2 * NTOK * DD, SAl + 2 * NTOK * DD,
            Oh, Ol, SS);
        gemm_mfma_k<2, 0><<<gP, blk, 0, stream>>>(Oh, Ol, Wh, Wl, oSAO,
            nullptr, 0, 0, Tb, nullptr, (int)NTOK, DD, DD, 0, 0, 0, flag);
        add_ln_k<<<NTOK, 256, 0, stream>>>(x, Tb, xh, xl, ln_g, oG, ln_b, oG, flag);
        // --- cross attention ---
        gemm_mfma_k<2, 1><<<gP, blk, 0, stream>>>(xh, xl, Wh, Wl, oCAQ,
            nullptr, 0, 0, Qh, Ql, (int)NTOK, DD, DD, 0, 0, 0, flag);
        gemm_mfma_k<1, 1><<<gCKV, blk, 0, stream>>>(encoded, nullptr, Wh, Wl, oCKV,
            nullptr, 0, 0, CKh, CKl, (int)NENC, 2 * DD, DD, 0, DD, NENC * DD, flag);
        attn_mfma_k<0><<<attn_blocks, 256, 0, stream>>>(Qh, Ql,
            CKh, CKl, CKh + NENC * DD, CKl + NENC * DD, Oh, Ol, MM);
        gemm_mfma_k<2, 0><<<gP, blk, 0, stream>>>(Oh, Ol, Wh, Wl, oCAO,
            nullptr, 0, 0, Tb, nullptr, (int)NTOK, DD, DD, 0, 0, 0, flag);
        add_ln_k<<<NTOK, 256, 0, stream>>>(x, Tb, xh, xl, ln_g, oG + DD, ln_b, oG + DD, flag);
        // --- FFN ---
        gemm_mfma_k<2, 1><<<gW1, blk, 0, stream>>>(xh, xl, Wh, Wl, oW1,
            ffn_b1, oB1, 1, Hh, Hl, (int)NTOK, FF, DD, 1, 0, 0, flag);
        gemm_mfma_k<2, 0><<<gP, blk, 0, stream>>>(Hh, Hl, Wh, Wl, oW2,
            ffn_b2, oB2, 1, Tb, nullptr, (int)NTOK, DD, FF, 0, 0, 0, flag);
        add_ln_k<<<NTOK, 256, 0, stream>>>(x, Tb, xh, xl, ln_g, oG + 2 * DD, ln_b, oG + 2 * DD, flag);
    }
    // final norm + shared-embedding logits
    add_ln_k<<<NTOK, 256, 0, stream>>>(x, nullptr, xh, xl, fin_g, 0, fin_b, 0, flag);
    gemm_mfma_k<2, 2><<<gOut, blk, 0, stream>>>(xh, xl, Wh, Wl, W_EMB0,
        (const char*)output_bias, 0, 1, d_out, nullptr, (int)NTOK, VV, DD, 0, 0, 0, flag);
}